// Round 1
// 327.130 us; speedup vs baseline: 1.0189x; 1.0189x over previous
//
#include <hip/hip_runtime.h>

#define LTC_B 512
#define LTC_H 512
#define LTC_I 256

static constexpr float kL2E = 1.4426950408889634f;  // log2(e)

// Pre-transformed weight pair (2 j's for one h), 16B:
// t = a*v + c (log2 domain), sig = 1/(1+2^t), n += wz*sig, d += wd*sig.
struct alignas(16) HPair { _Float16 a0, a1, c0, c1, wz0, wz1, wd0, wd1; };

typedef unsigned int u32;
#define AS_G __attribute__((address_space(1)))
#define AS_L __attribute__((address_space(3)))

__device__ __forceinline__ void ldg_lds16(const void* g, void* l) {
    // async global->LDS DMA, 16B/lane; LDS dest = wave-uniform base + lane*16
    __builtin_amdgcn_global_load_lds((const AS_G u32*)g, (AS_L u32*)l, 16, 0, 0);
}

// slab unit ((ht*(K/2) + jp)*64 + hh) holds j=2jp,2jp+1 for h=ht*64+hh.
// Any aligned jp-range of one h-tile is contiguous -> 8KB chunks DMA cleanly.
template<int K>
__global__ void ltc_prep(const float* __restrict__ mu, const float* __restrict__ sigma,
                         const float* __restrict__ W, const float* __restrict__ erev,
                         HPair* __restrict__ slab) {
    const int t = blockIdx.x * 256 + threadIdx.x;   // one thread per 16B unit
    if (t >= K * 256) return;
    const int hh   = t & 63;
    const int rest = t >> 6;
    const int jp   = rest & (K / 2 - 1);
    const int ht   = rest / (K / 2);
    const int h    = ht * 64 + hh;
    const int g0   = (2 * jp) * LTC_H + h;
    const int g1   = g0 + LTC_H;
    HPair o;
    o.a0 = (_Float16)(-sigma[g0] * kL2E);
    o.a1 = (_Float16)(-sigma[g1] * kL2E);
    o.c0 = (_Float16)(mu[g0] * sigma[g0] * kL2E);
    o.c1 = (_Float16)(mu[g1] * sigma[g1] * kL2E);
    o.wz0 = (_Float16)(W[g0] * erev[g0]);
    o.wz1 = (_Float16)(W[g1] * erev[g1]);
    o.wd0 = (_Float16)(W[g0]);
    o.wd1 = (_Float16)(W[g1]);
    slab[t] = o;
}

// j-split occupancy kernel: block = 512 thr (8 waves) covering 4 b-rows x 64 h.
// Waves 0-3 sum j in [0, K/2), waves 4-7 sum j in [K/2, K); partials combined
// in LDS at the end. Total waves double (8192 -> 32/CU = 100% wave occupancy)
// to fill the latency holes the 16-wave version left (each wave only ~14% busy).
// LDS: 2 j-streams x double-buffered 8KB chunks + 2KB combine = 34KB -> 4 blk/CU.
template<int K, bool RECUR>
__global__ __launch_bounds__(512, 8)
void ltc_pass(const float* __restrict__ vsrc,    // B x K
              const HPair* __restrict__ slab,    // [8][K/2][64]
              const float* __restrict__ snum, const float* __restrict__ sden,
              const float* __restrict__ vleak, const float* __restrict__ gleak,
              const float* __restrict__ cm,
              float* __restrict__ onum, float* __restrict__ oden,
              float* __restrict__ vout)
{
    __shared__ HPair wbuf[2][2][8 * 64];         // [jh][dbuf][8KB] = 32KB
    __shared__ float comb[4][2][64];             // jh=1 partials (na,da), 2KB

    const int tid  = threadIdx.x;
    const int lane = tid & 63;
    const int wu   = __builtin_amdgcn_readfirstlane(tid >> 6);  // uniform wave id
    const int bw   = wu & 3;                     // b within block
    const int jh   = wu >> 2;                    // j-half (0 or 1)
    const int ht   = blockIdx.x;                 // 0..7
    const int b    = blockIdx.y * 4 + bw;        // uniform per wave
    const float* __restrict__ vrow = vsrc + (size_t)b * K + jh * (K / 2);

    constexpr int NCH = K / 32;                  // 16-j (8KB) chunks per j-half
    const int rot = (int)((blockIdx.x + 7u * blockIdx.y) & (NCH - 1));
    // half-slab base: ht slice is K*512 bytes; each j-half is K*256 bytes
    const char* slabt = (const char*)slab + (size_t)ht * (K * 512) + (size_t)jh * (K * 256);

    // prefetch first chunk of this wave's stream (wave stages its 2KB quarter)
    {
        const char* src = slabt + rot * 8192 + bw * 2048;
        char* dst = (char*)&wbuf[jh][0][0] + bw * 2048;
        ldg_lds16(src + lane * 16, dst);
        ldg_lds16(src + 1024 + lane * 16, dst + 1024);
    }

    float na = 0.f, da = 0.f;

    #pragma unroll
    for (int i = 0; i < NCH; ++i) {
        const int c = (rot + i) & (NCH - 1);
        __syncthreads();                         // drains this wave's DMA + joins
        if (i + 1 < NCH) {                       // DMA i+1 flies during compute i
            const int cn = (rot + i + 1) & (NCH - 1);
            const char* src = slabt + cn * 8192 + bw * 2048;
            char* dst = (char*)&wbuf[jh][(i + 1) & 1][0] + bw * 2048;
            ldg_lds16(src + lane * 16, dst);
            ldg_lds16(src + 1024 + lane * 16, dst + 1024);
        }
        const HPair* wb = &wbuf[jh][i & 1][0];
        const float* __restrict__ vch = vrow + c * 16;

        HPair pr[8];                             // grouped ds_read_b128
        #pragma unroll
        for (int jj = 0; jj < 8; ++jj) pr[jj] = wb[jj * 64 + lane];

        #pragma unroll
        for (int jj = 0; jj < 8; ++jj) {
            const float vj0 = vch[2 * jj];       // uniform scalar loads
            const float vj1 = vch[2 * jj + 1];
            const float t0 = fmaf((float)pr[jj].a0, vj0, (float)pr[jj].c0);
            const float t1 = fmaf((float)pr[jj].a1, vj1, (float)pr[jj].c1);
            const float e0 = __builtin_amdgcn_exp2f(t0);
            const float e1 = __builtin_amdgcn_exp2f(t1);
            const float d0 = 1.0f + e0;
            const float d1 = 1.0f + e1;
            const float rr = __builtin_amdgcn_rcpf(d0 * d1);  // 1 rcp / 2 sigmoids
            const float s0 = rr * d1;
            const float s1 = rr * d0;
            na = fmaf((float)pr[jj].wz0, s0, na);
            da = fmaf((float)pr[jj].wd0, s0, da);
            na = fmaf((float)pr[jj].wz1, s1, na);
            da = fmaf((float)pr[jj].wd1, s1, da);
        }
    }

    // combine the two j-half partials inside the block
    if (jh == 1) { comb[bw][0][lane] = na; comb[bw][1][lane] = da; }
    __syncthreads();
    if (jh == 0) {
        na += comb[bw][0][lane];
        da += comb[bw][1][lane];
        const int h  = ht * 64 + lane;
        const int bh = b * LTC_H + h;
        if constexpr (RECUR) {
            const float gl = gleak[h], vl = vleak[h], c0 = cm[h];
            const float vp = vsrc[bh];           // K==H here
            const float num = fmaf(c0, vp, gl * vl) + na + snum[bh];
            const float den = c0 + gl + da + sden[bh];
            vout[bh] = num * __builtin_amdgcn_rcpf(den + 1e-8f);
        } else {
            onum[bh] = na;
            oden[bh] = da;
        }
    }
}

extern "C" void kernel_launch(void* const* d_in, const int* in_sizes, int n_in,
                              void* d_out, int out_size, void* d_ws, size_t ws_size,
                              hipStream_t stream) {
    const float* inputs = (const float*)d_in[0];   // B x I
    const float* state  = (const float*)d_in[1];   // B x H
    const float* smu    = (const float*)d_in[2];   // I x H
    const float* ssig   = (const float*)d_in[3];
    const float* sW     = (const float*)d_in[4];
    const float* serev  = (const float*)d_in[5];
    const float* mu     = (const float*)d_in[6];   // H x H
    const float* sig    = (const float*)d_in[7];
    const float* W      = (const float*)d_in[8];
    const float* erev   = (const float*)d_in[9];
    const float* vleak  = (const float*)d_in[10];  // H
    const float* gleak  = (const float*)d_in[11];
    const float* cm     = (const float*)d_in[12];

    float* out  = (float*)d_out;                   // B x H
    char*  ws   = (char*)d_ws;
    float* snum = (float*)(ws);                              // 1MB
    float* sden = (float*)(ws + 1 * 1048576);                // 1MB
    float* vA   = (float*)(ws + 2 * 1048576);                // 1MB ping buffer
    HPair* rslab = (HPair*)(ws + 3 * 1048576);               // 2MB (H x H)
    HPair* sslab = (HPair*)(ws + 5 * 1048576);               // 1MB (I x H)

    // Prep: transform + pair-pack weights once per launch (coalesced 16B writes).
    ltc_prep<LTC_H><<<LTC_H * 256 / 256, 256, 0, stream>>>(mu, sig, W, erev, rslab);
    ltc_prep<LTC_I><<<LTC_I * 256 / 256, 256, 0, stream>>>(smu, ssig, sW, serev, sslab);

    dim3 grid(LTC_H / 64, LTC_B / 4);              // (8, 128) = 1024 blocks
    dim3 blk(512);                                 // 8 waves: 4 b x 2 j-halves

    // Sensory pass: raw sums into ws.
    ltc_pass<LTC_I, false><<<grid, blk, 0, stream>>>(
        inputs, sslab, nullptr, nullptr, nullptr, nullptr, nullptr,
        snum, sden, nullptr);

    // 6 unfolds, ping-ponging so the last lands in d_out.
    const float* vin = state;
    float* targets[6] = {vA, out, vA, out, vA, out};
    for (int s = 0; s < 6; ++s) {
        ltc_pass<LTC_H, true><<<grid, blk, 0, stream>>>(
            vin, rslab, snum, sden, vleak, gleak, cm,
            nullptr, nullptr, targets[s]);
        vin = targets[s];
    }
}

// Round 2
// 305.781 us; speedup vs baseline: 1.0900x; 1.0698x over previous
//
#include <hip/hip_runtime.h>

#define LTC_B 512
#define LTC_H 512
#define LTC_I 256

static constexpr float kL2E = 1.4426950408889634f;  // log2(e)

// Pre-transformed weight pair (2 j's for one h), 16B:
// t = a*v + c (log2 domain), sig = 1/(1+2^t), n += wz*sig, d += wd*sig.
struct alignas(16) HPair { _Float16 a0, a1, c0, c1, wz0, wz1, wd0, wd1; };

// slab unit ((ht*(K/2) + jp)*64 + hh) holds j=2jp,2jp+1 for h=ht*64+hh.
// Consecutive hh = consecutive 16B units -> one global_load_dwordx4 per lane
// is a perfectly coalesced 1KB wave read.
template<int K>
__global__ void ltc_prep(const float* __restrict__ mu, const float* __restrict__ sigma,
                         const float* __restrict__ W, const float* __restrict__ erev,
                         HPair* __restrict__ slab) {
    const int t = blockIdx.x * 256 + threadIdx.x;   // one thread per 16B unit
    if (t >= K * 256) return;
    const int hh   = t & 63;
    const int rest = t >> 6;
    const int jp   = rest & (K / 2 - 1);
    const int ht   = rest / (K / 2);
    const int h    = ht * 64 + hh;
    const int g0   = (2 * jp) * LTC_H + h;
    const int g1   = g0 + LTC_H;
    HPair o;
    o.a0 = (_Float16)(-sigma[g0] * kL2E);
    o.a1 = (_Float16)(-sigma[g1] * kL2E);
    o.c0 = (_Float16)(mu[g0] * sigma[g0] * kL2E);
    o.c1 = (_Float16)(mu[g1] * sigma[g1] * kL2E);
    o.wz0 = (_Float16)(W[g0] * erev[g0]);
    o.wz1 = (_Float16)(W[g1] * erev[g1]);
    o.wd0 = (_Float16)(W[g0]);
    o.wd1 = (_Float16)(W[g1]);
    slab[t] = o;
}

// Register-direct kernel: block = 512 thr = 8 waves, all covering the SAME
// 4 b-rows x 64 h; wave w owns j-slice w of 8 (8-way j-split -> 8192 waves =
// 32/CU). Weights go global->VGPR directly (double-buffered 2-pair chunks,
// compiler-managed vmcnt) -- no LDS staging, NO barriers in the main loop:
// latency is hidden by 32 independent waves instead of lockstep DMA phases.
// The f16->f32 weight conversions amortize over 4 b (was the single largest
// VALU term at 8/19 ops per pair-eval).
template<int K, bool RECUR>
__global__ __launch_bounds__(512, 8)
void ltc_pass(const float* __restrict__ vsrc,    // B x K
              const HPair* __restrict__ slab,    // [8][K/2][64]
              const float* __restrict__ snum, const float* __restrict__ sden,
              const float* __restrict__ vleak, const float* __restrict__ gleak,
              const float* __restrict__ cm,
              float* __restrict__ onum, float* __restrict__ oden,
              float* __restrict__ vout)
{
    constexpr int JQ = 8;                // j-slices = waves per block
    constexpr int PW = (K / 2) / JQ;     // pairs per wave: 32 (K=512) / 16
    constexpr int CP = 2;                // pairs per register chunk
    constexpr int NC = PW / CP;          // chunks per wave: 16 / 8

    __shared__ float comb[JQ][4][64][2]; // 16 KB: per-wave (na,da) x 4 b

    const int tid  = threadIdx.x;
    const int lane = tid & 63;
    const int wu   = __builtin_amdgcn_readfirstlane(tid >> 6);  // j-slice id
    const int ht   = blockIdx.x;                 // 0..7
    const int b0   = blockIdx.y * 4;

    // this wave's weight slice: pairs [wu*PW, (wu+1)*PW) of h-tile ht
    const HPair* __restrict__ wp =
        slab + ((size_t)ht * (K / 2) + (size_t)wu * PW) * 64 + lane;
    // uniform v rows (scalar loads), offset to this wave's j-slice
    const float* __restrict__ v0 = vsrc + (size_t)(b0 + 0) * K + wu * (2 * PW);
    const float* __restrict__ v1 = vsrc + (size_t)(b0 + 1) * K + wu * (2 * PW);
    const float* __restrict__ v2 = vsrc + (size_t)(b0 + 2) * K + wu * (2 * PW);
    const float* __restrict__ v3 = vsrc + (size_t)(b0 + 3) * K + wu * (2 * PW);

    float na0 = 0.f, da0 = 0.f, na1 = 0.f, da1 = 0.f;
    float na2 = 0.f, da2 = 0.f, na3 = 0.f, da3 = 0.f;

    // one pair-eval for 4 b's: 8 cvt (shared) + 11 VALU + 3 trans per b
    auto evalp = [&](const HPair& pr, int p) {
        const float a0f = (float)pr.a0, a1f = (float)pr.a1;
        const float c0f = (float)pr.c0, c1f = (float)pr.c1;
        const float wz0f = (float)pr.wz0, wz1f = (float)pr.wz1;
        const float wd0f = (float)pr.wd0, wd1f = (float)pr.wd1;
#define LTC_ONEB(vb, nab, dab)                                             \
        {                                                                  \
            const float t0 = fmaf(a0f, vb[2 * p], c0f);                    \
            const float t1 = fmaf(a1f, vb[2 * p + 1], c1f);                \
            const float e0 = __builtin_amdgcn_exp2f(t0);                   \
            const float e1 = __builtin_amdgcn_exp2f(t1);                   \
            const float d0 = 1.0f + e0;                                    \
            const float d1 = 1.0f + e1;                                    \
            const float rr = __builtin_amdgcn_rcpf(d0 * d1);               \
            const float s0 = rr * d1;                                      \
            const float s1 = rr * d0;                                      \
            nab = fmaf(wz0f, s0, nab);                                     \
            dab = fmaf(wd0f, s0, dab);                                     \
            nab = fmaf(wz1f, s1, nab);                                     \
            dab = fmaf(wd1f, s1, dab);                                     \
        }
        LTC_ONEB(v0, na0, da0)
        LTC_ONEB(v1, na1, da1)
        LTC_ONEB(v2, na2, da2)
        LTC_ONEB(v3, na3, da3)
#undef LTC_ONEB
    };

    HPair bA[CP], bB[CP];
    #pragma unroll
    for (int q = 0; q < CP; ++q) bA[q] = wp[(0 * CP + q) * 64];
    #pragma unroll
    for (int q = 0; q < CP; ++q) bB[q] = wp[(1 * CP + q) * 64];

    #pragma unroll
    for (int ch = 0; ch < NC; ch += 2) {
        #pragma unroll
        for (int q = 0; q < CP; ++q) evalp(bA[q], ch * CP + q);
        if (ch + 2 < NC) {
            #pragma unroll
            for (int q = 0; q < CP; ++q) bA[q] = wp[((ch + 2) * CP + q) * 64];
        }
        #pragma unroll
        for (int q = 0; q < CP; ++q) evalp(bB[q], (ch + 1) * CP + q);
        if (ch + 3 < NC) {
            #pragma unroll
            for (int q = 0; q < CP; ++q) bB[q] = wp[((ch + 3) * CP + q) * 64];
        }
    }

    // combine 8 j-slice partials per (b, h) in-block (single barrier)
    comb[wu][0][lane][0] = na0; comb[wu][0][lane][1] = da0;
    comb[wu][1][lane][0] = na1; comb[wu][1][lane][1] = da1;
    comb[wu][2][lane][0] = na2; comb[wu][2][lane][1] = da2;
    comb[wu][3][lane][0] = na3; comb[wu][3][lane][1] = da3;
    __syncthreads();

    if (wu < 4) {
        float na = 0.f, da = 0.f;
        #pragma unroll
        for (int jq = 0; jq < JQ; ++jq) {
            na += comb[jq][wu][lane][0];
            da += comb[jq][wu][lane][1];
        }
        const int b  = b0 + wu;
        const int h  = ht * 64 + lane;
        const int bh = b * LTC_H + h;
        if constexpr (RECUR) {
            const float gl = gleak[h], vl = vleak[h], c0 = cm[h];
            const float vp = vsrc[bh];           // K==H here
            const float num = fmaf(c0, vp, gl * vl) + na + snum[bh];
            const float den = c0 + gl + da + sden[bh];
            vout[bh] = num * __builtin_amdgcn_rcpf(den + 1e-8f);
        } else {
            onum[bh] = na;
            oden[bh] = da;
        }
    }
}

extern "C" void kernel_launch(void* const* d_in, const int* in_sizes, int n_in,
                              void* d_out, int out_size, void* d_ws, size_t ws_size,
                              hipStream_t stream) {
    const float* inputs = (const float*)d_in[0];   // B x I
    const float* state  = (const float*)d_in[1];   // B x H
    const float* smu    = (const float*)d_in[2];   // I x H
    const float* ssig   = (const float*)d_in[3];
    const float* sW     = (const float*)d_in[4];
    const float* serev  = (const float*)d_in[5];
    const float* mu     = (const float*)d_in[6];   // H x H
    const float* sig    = (const float*)d_in[7];
    const float* W      = (const float*)d_in[8];
    const float* erev   = (const float*)d_in[9];
    const float* vleak  = (const float*)d_in[10];  // H
    const float* gleak  = (const float*)d_in[11];
    const float* cm     = (const float*)d_in[12];

    float* out  = (float*)d_out;                   // B x H
    char*  ws   = (char*)d_ws;
    float* snum = (float*)(ws);                              // 1MB
    float* sden = (float*)(ws + 1 * 1048576);                // 1MB
    float* vA   = (float*)(ws + 2 * 1048576);                // 1MB ping buffer
    HPair* rslab = (HPair*)(ws + 3 * 1048576);               // 2MB (H x H)
    HPair* sslab = (HPair*)(ws + 5 * 1048576);               // 1MB (I x H)

    // Prep: transform + pair-pack weights once per launch (coalesced 16B writes).
    ltc_prep<LTC_H><<<LTC_H * 256 / 256, 256, 0, stream>>>(mu, sig, W, erev, rslab);
    ltc_prep<LTC_I><<<LTC_I * 256 / 256, 256, 0, stream>>>(smu, ssig, sW, serev, sslab);

    dim3 grid(LTC_H / 64, LTC_B / 4);              // (8, 128) = 1024 blocks
    dim3 blk(512);                                 // 8 waves: 8 j-slices x (4b x 64h)

    // Sensory pass: raw sums into ws.
    ltc_pass<LTC_I, false><<<grid, blk, 0, stream>>>(
        inputs, sslab, nullptr, nullptr, nullptr, nullptr, nullptr,
        snum, sden, nullptr);

    // 6 unfolds, ping-ponging so the last lands in d_out.
    const float* vin = state;
    float* targets[6] = {vA, out, vA, out, vA, out};
    for (int s = 0; s < 6; ++s) {
        ltc_pass<LTC_H, true><<<grid, blk, 0, stream>>>(
            vin, rslab, snum, sden, vleak, gleak, cm,
            nullptr, nullptr, targets[s]);
        vin = targets[s];
    }
}

// Round 4
// 291.525 us; speedup vs baseline: 1.1433x; 1.0489x over previous
//
#include <hip/hip_runtime.h>

#define LTC_B 512
#define LTC_H 512
#define LTC_I 256

static constexpr float kL2E = 1.4426950408889634f;  // log2(e)

// f32 weight quad per (j,h): a = -sigma*log2(e), ec = 2^(mu*sigma*log2(e)),
// wz = W*erev, wd = W.  sigma(b,j,h) = 1 / (1 + ec * 2^(a*v(b,j))).
// Layout: quad index = (ht4*K + j)*4 + hh4 with h = ht4*4 + hh4 -> the 4 h's
// of one (ht4,j) are a contiguous 64B group: one s_load_dwordx16 per j.
// ONE THREAD PER (j,h) QUAD: total K*LTC_H threads (R3 bug: was /4 -> 3/4 of
// the slab stayed zero and h>=128 columns collapsed to the leak-only path).
template<int K, int LOG2K>
__global__ void ltc_prep(const float* __restrict__ mu, const float* __restrict__ sigma,
                         const float* __restrict__ W, const float* __restrict__ erev,
                         float4* __restrict__ slab) {
    const int t = blockIdx.x * 256 + threadIdx.x;   // one thread per quad
    if (t >= K * LTC_H) return;
    const int hh4  = t & 3;
    const int rest = t >> 2;
    const int j    = rest & (K - 1);
    const int ht4  = rest >> LOG2K;
    const int h    = ht4 * 4 + hh4;
    const int g    = j * LTC_H + h;
    const float sg = sigma[g];
    float4 o;
    o.x = -sg * kL2E;                    // a
    o.y = exp2f(mu[g] * sg * kL2E);      // ec = 2^c
    o.z = W[g] * erev[g];                // wz
    o.w = W[g];                          // wd
    slab[t] = o;                         // coalesced 16B/lane
}

// 64x64 LDS tile transpose: in R x C -> out C x R. grid (C/64, R/64), 256 thr.
__global__ void ltc_transpose(const float* __restrict__ in, float* __restrict__ out,
                              int R, int C) {
    __shared__ float tile[64][65];
    const int bx = blockIdx.x * 64;      // col base
    const int by = blockIdx.y * 64;      // row base
    const int tx = threadIdx.x & 63;
    const int t4 = threadIdx.x >> 6;
    #pragma unroll
    for (int r = t4; r < 64; r += 4)
        tile[r][tx] = in[(size_t)(by + r) * C + bx + tx];
    __syncthreads();
    #pragma unroll
    for (int r = t4; r < 64; r += 4)
        out[(size_t)(bx + r) * R + by + tx] = tile[tx][r];
}

// Lane = BATCH kernel. Block = 512 thr = 8 waves = 8 j-slices, all for the
// same (4-h tile ht4, 64-b wave bw). Weights are wave-uniform -> stream via
// s_load into SGPRs (scalar pipe), v(b,j) is a coalesced per-lane load.
// Per (j,h) eval over 64 b: e=exp2(a*v) [1 SGPR], d=fma(ec,e,1) [1 SGPR+inline],
// paired-rcp, accum fma [1 SGPR] -- 5.5 full-rate VALU + 1.5 trans per sigmoid,
// no f16 cvt, no per-lane weight traffic, no barriers in the main loop.
// MODE: 0 = sensory (write snumT/sdenT), 1 = recurrent (write vT KxB),
//       2 = last recurrent (write out B x H).
template<int K, int MODE>
__global__ __launch_bounds__(512, 8)
void ltc_pass(const float* __restrict__ vT,      // K x B (transposed)
              const float4* __restrict__ slab,   // [128][K][4]
              const float* __restrict__ snumT, const float* __restrict__ sdenT, // H x B
              const float* __restrict__ vleak, const float* __restrict__ gleak,
              const float* __restrict__ cm,
              float* __restrict__ o0, float* __restrict__ o1)
{
    constexpr int JW = K / 8;                    // j's per wave
    __shared__ float2 comb[8][4][64];            // 16 KB partials

    const int tid  = threadIdx.x;
    const int lane = tid & 63;
    const int wu   = __builtin_amdgcn_readfirstlane(tid >> 6);  // j-slice
    const int ht4  = blockIdx.x;                 // 0..127: 4-h tile
    const int b0   = blockIdx.y * 64;            // 0..7 -> b base

    const float4* __restrict__ wq = slab + ((size_t)ht4 * K + wu * JW) * 4;
    const float*  __restrict__ vp = vT + (size_t)(wu * JW) * LTC_B + b0 + lane;

    float na0 = 0.f, da0 = 0.f, na1 = 0.f, da1 = 0.f;
    float na2 = 0.f, da2 = 0.f, na3 = 0.f, da3 = 0.f;

    #pragma unroll 4
    for (int jj = 0; jj < JW; ++jj) {
        const float vj = vp[(size_t)jj * LTC_B]; // per-lane, coalesced
        const float4 q0 = wq[jj * 4 + 0];        // wave-uniform -> s_load
        const float4 q1 = wq[jj * 4 + 1];
        const float4 q2 = wq[jj * 4 + 2];
        const float4 q3 = wq[jj * 4 + 3];
        const float e0 = __builtin_amdgcn_exp2f(q0.x * vj);
        const float e1 = __builtin_amdgcn_exp2f(q1.x * vj);
        const float e2 = __builtin_amdgcn_exp2f(q2.x * vj);
        const float e3 = __builtin_amdgcn_exp2f(q3.x * vj);
        const float d0 = fmaf(q0.y, e0, 1.0f);
        const float d1 = fmaf(q1.y, e1, 1.0f);
        const float d2 = fmaf(q2.y, e2, 1.0f);
        const float d3 = fmaf(q3.y, e3, 1.0f);
        const float r01 = __builtin_amdgcn_rcpf(d0 * d1);  // 1 rcp / 2 sigmoids
        const float r23 = __builtin_amdgcn_rcpf(d2 * d3);
        const float s0 = r01 * d1, s1 = r01 * d0;
        const float s2 = r23 * d3, s3 = r23 * d2;
        na0 = fmaf(q0.z, s0, na0); da0 = fmaf(q0.w, s0, da0);
        na1 = fmaf(q1.z, s1, na1); da1 = fmaf(q1.w, s1, da1);
        na2 = fmaf(q2.z, s2, na2); da2 = fmaf(q2.w, s2, da2);
        na3 = fmaf(q3.z, s3, na3); da3 = fmaf(q3.w, s3, da3);
    }

    comb[wu][0][lane] = make_float2(na0, da0);
    comb[wu][1][lane] = make_float2(na1, da1);
    comb[wu][2][lane] = make_float2(na2, da2);
    comb[wu][3][lane] = make_float2(na3, da3);
    __syncthreads();

    if (wu < 4) {                                // wave wu finishes h = ht4*4+wu
        float na = 0.f, da = 0.f;
        #pragma unroll
        for (int js = 0; js < 8; ++js) {
            const float2 p = comb[js][wu][lane];
            na += p.x; da += p.y;
        }
        const int h = ht4 * 4 + wu;
        const int b = b0 + lane;
        const size_t hb = (size_t)h * LTC_B + b;
        if constexpr (MODE == 0) {
            o0[hb] = na;                         // snumT (coalesced)
            o1[hb] = da;                         // sdenT
        } else {
            const float gl = gleak[h], vl = vleak[h], c0 = cm[h];
            const float vpre = vT[hb];           // K==H here, coalesced
            const float num = fmaf(c0, vpre, gl * vl) + na + snumT[hb];
            const float den = c0 + gl + da + sdenT[hb];
            const float vn = num * __builtin_amdgcn_rcpf(den + 1e-8f);
            if constexpr (MODE == 1) o0[hb] = vn;            // vT_next
            else o0[(size_t)b * LTC_H + h] = vn;             // final B x H
        }
    }
}

extern "C" void kernel_launch(void* const* d_in, const int* in_sizes, int n_in,
                              void* d_out, int out_size, void* d_ws, size_t ws_size,
                              hipStream_t stream) {
    const float* inputs = (const float*)d_in[0];   // B x I
    const float* state  = (const float*)d_in[1];   // B x H
    const float* smu    = (const float*)d_in[2];   // I x H
    const float* ssig   = (const float*)d_in[3];
    const float* sW     = (const float*)d_in[4];
    const float* serev  = (const float*)d_in[5];
    const float* mu     = (const float*)d_in[6];   // H x H
    const float* sig    = (const float*)d_in[7];
    const float* W      = (const float*)d_in[8];
    const float* erev   = (const float*)d_in[9];
    const float* vleak  = (const float*)d_in[10];  // H
    const float* gleak  = (const float*)d_in[11];
    const float* cm     = (const float*)d_in[12];

    float* out = (float*)d_out;                    // B x H
    char*  ws  = (char*)d_ws;
    float*  snumT = (float*)(ws);                            // 1MB  H x B
    float*  sdenT = (float*)(ws + 1 * 1048576);              // 1MB  H x B
    float*  vTA   = (float*)(ws + 2 * 1048576);              // 1MB  H x B
    float*  vTB   = (float*)(ws + 3 * 1048576);              // 1MB  H x B
    float4* rslab = (float4*)(ws + 4 * 1048576);             // 4MB  [128][512][4]
    float4* sslab = (float4*)(ws + 8 * 1048576);             // 2MB  [128][256][4]
    float*  inpT  = (float*)(ws + 10 * 1048576);             // 0.5MB I x B

    // Weight transform (f32 quads, once per launch). One thread per (j,h).
    ltc_prep<LTC_H, 9><<<LTC_H * LTC_H / 256, 256, 0, stream>>>(mu, sig, W, erev, rslab);
    ltc_prep<LTC_I, 8><<<LTC_I * LTC_H / 256, 256, 0, stream>>>(smu, ssig, sW, serev, sslab);

    // Transpose activations into K x B layout.
    ltc_transpose<<<dim3(LTC_I / 64, LTC_B / 64), 256, 0, stream>>>(inputs, inpT, LTC_B, LTC_I);
    ltc_transpose<<<dim3(LTC_H / 64, LTC_B / 64), 256, 0, stream>>>(state, vTA, LTC_B, LTC_H);

    dim3 grid(LTC_H / 4, LTC_B / 64);              // (128 h-tiles, 8 b-waves)
    dim3 blk(512);

    // Sensory pass -> snumT/sdenT (H x B).
    ltc_pass<LTC_I, 0><<<grid, blk, 0, stream>>>(
        inpT, sslab, nullptr, nullptr, nullptr, nullptr, nullptr, snumT, sdenT);

    // 6 unfolds: vTA -> vTB -> ... ; last writes B x H into d_out.
    const float* vin = vTA;
    float* vping[5] = {vTB, vTA, vTB, vTA, vTB};
    for (int s = 0; s < 5; ++s) {
        ltc_pass<LTC_H, 1><<<grid, blk, 0, stream>>>(
            vin, rslab, snumT, sdenT, vleak, gleak, cm, vping[s], nullptr);
        vin = vping[s];
    }
    ltc_pass<LTC_H, 2><<<grid, blk, 0, stream>>>(
        vin, rslab, snumT, sdenT, vleak, gleak, cm, out, nullptr);
}